// Round 1
// 461.062 us; speedup vs baseline: 1.0236x; 1.0236x over previous
//
#include <hip/hip_runtime.h>
#include <hip/hip_bf16.h>

// out[b,s,o] = sum_i x[b,s,i] * w[o,i]  -- NT GEMM M=8192, N=4096, K=4096
// w dequantized from 4-bit groups (256 vals/group, 16 groups per output row).

#define M_DIM 8192
#define N_DIM 4096
#define K_DIM 4096

typedef __bf16 bf16x8 __attribute__((ext_vector_type(8)));
typedef float f32x4 __attribute__((ext_vector_type(4)));
typedef unsigned short us8 __attribute__((ext_vector_type(8)));

__device__ __forceinline__ unsigned short f2bf_rne(float f) {
    unsigned int u = __builtin_bit_cast(unsigned int, f);
    u += 0x7FFFu + ((u >> 16) & 1u);
    return (unsigned short)(u >> 16);
}

// ---- fused prepass (unchanged) ---------------------------------------------
// blocks [0,16384): x fp32 -> bf16, 8 floats/thread (16 B store)
// blocks [16384,24576): dequant 4-bit -> bf16 W[N][K], 4 packed ints/thread
__global__ void prep_kernel(const float* __restrict__ x,
                            const int* __restrict__ packed,
                            const float* __restrict__ params,
                            ushort* __restrict__ a,
                            ushort* __restrict__ w) {
    int b = blockIdx.x;
    if (b < 16384) {
        int j = b * 256 + threadIdx.x;        // ushort8 index
        float4 v0 = ((const float4*)x)[2 * j];
        float4 v1 = ((const float4*)x)[2 * j + 1];
        us8 o;
        o[0] = f2bf_rne(v0.x); o[1] = f2bf_rne(v0.y);
        o[2] = f2bf_rne(v0.z); o[3] = f2bf_rne(v0.w);
        o[4] = f2bf_rne(v1.x); o[5] = f2bf_rne(v1.y);
        o[6] = f2bf_rne(v1.z); o[7] = f2bf_rne(v1.w);
        ((us8*)a)[j] = o;
    } else {
        int j = (b - 16384) * 256 + threadIdx.x;   // int4 index
        int4 v = ((const int4*)packed)[j];
        int g = j >> 5;                            // 4 ints same group
        float s = params[2 * g], z = params[2 * g + 1];
        unsigned int o0, o1, o2, o3;
        o0 = (unsigned int)f2bf_rne((float)(v.x & 15) * s + z)
           | ((unsigned int)f2bf_rne((float)((v.x >> 4) & 15) * s + z) << 16);
        o1 = (unsigned int)f2bf_rne((float)(v.y & 15) * s + z)
           | ((unsigned int)f2bf_rne((float)((v.y >> 4) & 15) * s + z) << 16);
        o2 = (unsigned int)f2bf_rne((float)(v.z & 15) * s + z)
           | ((unsigned int)f2bf_rne((float)((v.z >> 4) & 15) * s + z) << 16);
        o3 = (unsigned int)f2bf_rne((float)(v.w & 15) * s + z)
           | ((unsigned int)f2bf_rne((float)((v.w >> 4) & 15) * s + z) << 16);
        ((uint4*)w)[j] = make_uint4(o0, o1, o2, o3);
    }
}

// ---- main GEMM: 256x256 tile, BK=64, 8-phase counted-vmcnt schedule --------
// C[M][N] = A[M][K] * B[N][K]^T, bf16 in, fp32 out.
// 8 waves (2M x 4N), each wave owns a 128x64 output (8x4 frags of 16x16).
// LDS 128 KiB = {A,B} x {buf0,buf1} x {half0,half1}, half = 128x64 bf16 = 16 KiB.
// Chunk-XOR swizzle (16B granule): slot chunk c holds global chunk c^(row&7);
// applied on the pre-swizzled global_load_lds SOURCE and on the ds_read side
// (both-sides involution) -> measured 0 bank conflicts with this read pattern.
//
// Per K-tile (4 phases): phase q0 ds-reads the tile's 8 B-frags (held in regs
// for all 4 phases) + quadrant-0 A-frags; q1..q3 read 4 A-frags each. Each
// phase issues ONE half-tile prefetch (2x global_load_lds w=16). Ledger:
//   iter i phases: 1:A(2i+1)h0 2:A(2i+1)h1 3:B(2i+2)h0 4:B(2i+2)h1+vmcnt(4)
//                  5:A(2i+2)h0 6:A(2i+2)h1 7:B(2i+3)h0 8:B(2i+3)h1+vmcnt(4)
// Slot-free proof: B-slots of tile t are dead after phase 4t+0's end barrier
// (B-frags hoisted to regs in q0); A-slots dead after phase 4t+3's end
// barrier. Every issue above lands strictly after its slot frees.
// vmcnt(4) = 2 half-tiles in flight; never drained to 0 in the loop.
// Tail: prefetch source k clamped to last tile (slots unread, ledger intact).
__global__ __launch_bounds__(512, 2) void gemm_bt(const ushort* __restrict__ A,
                                                  const ushort* __restrict__ B,
                                                  float* __restrict__ C) {
    __shared__ ushort lds[65536];   // 128 KiB: A slots [0,32768), B [32768,65536)

    const int tid  = threadIdx.x;
    const int w    = tid >> 6;           // wave 0..7
    const int lane = tid & 63;
    const int quad = lane >> 4;          // 0..3
    const int l16  = lane & 15;
    const int wm   = w >> 2;             // wave M index 0..1 (128 rows each)
    const int wn   = w & 3;              // wave N index 0..3 (64 cols each)

    // XCD-bijective swizzle: 512 blocks, 8 XCDs, 64 contiguous per XCD.
    // B-panel-major: one XCD covers 2 N-columns (4.2 MB B panel ~ L2).
    const int bid = blockIdx.x;
    const int sid = (bid & 7) * 64 + (bid >> 3);
    const int by  = sid & 31;            // M tile 0..31
    const int bx  = sid >> 5;            // N tile 0..15
    const int m0  = by * 256;
    const int n0  = bx * 256;

    // staging source bases: thread t covers half-row (t>>3), swizzled chunk
    const int srow = tid >> 3;                       // 0..63
    const int scol = ((tid & 7) ^ (srow & 7)) * 8;   // pre-swizzled k-offset
    const ushort* aS = A + (size_t)(m0 + srow) * K_DIM + scol;
    const ushort* bS = B + (size_t)(n0 + srow) * K_DIM + scol;

    f32x4 acc[8][4] = {};

    // stage one half-tile (128x64) = 2 x global_load_lds(16B) per thread.
    // LDS dest is linear (wave-uniform base, HW adds lane*16).
    auto stageA = [&](int t, int h) {
        const int kc   = (t < 64 ? t : 63) * 64;
        const int slot = ((t & 1) * 2 + h) * 8192;   // element offset
#pragma unroll
        for (int l = 0; l < 2; ++l)
            __builtin_amdgcn_global_load_lds(
                (const __attribute__((address_space(1))) void*)(aS + (size_t)(h * 128 + l * 64) * K_DIM + kc),
                (__attribute__((address_space(3))) void*)(lds + slot + (l * 512 + w * 64) * 8),
                16, 0, 0);
    };
    auto stageB = [&](int t, int h) {
        const int kc   = (t < 64 ? t : 63) * 64;
        const int slot = 32768 + ((t & 1) * 2 + h) * 8192;
#pragma unroll
        for (int l = 0; l < 2; ++l)
            __builtin_amdgcn_global_load_lds(
                (const __attribute__((address_space(1))) void*)(bS + (size_t)(h * 128 + l * 64) * K_DIM + kc),
                (__attribute__((address_space(3))) void*)(lds + slot + (l * 512 + w * 64) * 8),
                16, 0, 0);
    };

    // prologue: B0h0 B0h1 A0h0 A0h1 B1h0 B1h1; wait tile0 landed (12-4=8 loads)
    stageB(0, 0); stageB(0, 1); stageA(0, 0); stageA(0, 1); stageB(1, 0); stageB(1, 1);
    asm volatile("s_waitcnt vmcnt(4)" ::: "memory");
    __builtin_amdgcn_s_barrier();

    const int aBase = wm * 8192;                   // this wave's A half-slot
    const int bBase = 32768 + (wn >> 1) * 8192;    // this wave's B half-slot
    const int bR0   = (wn & 1) * 64;               // B row offset within half
    const int swz8  = l16 & 7;

#pragma unroll 1
    for (int i = 0; i < 32; ++i) {
#pragma unroll
        for (int hh = 0; hh < 2; ++hh) {
            const int tc  = 2 * i + hh;            // current tile (tc&1 == hh)
            const int buf = hh * 16384;            // K-tile parity buffer
            const int sa  = 2 * i + 1 + hh;        // A prefetch tile
            const int sb  = 2 * i + 2 + hh;        // B prefetch tile
            bf16x8 bf[4][2];
#pragma unroll
            for (int q = 0; q < 4; ++q) {
                if (q == 0) {                       // hoist tile's B-frags
#pragma unroll
                    for (int j = 0; j < 4; ++j)
#pragma unroll
                        for (int ks = 0; ks < 2; ++ks) {
                            const int r = bR0 + j * 16 + l16;
                            const int c = (ks * 4 + quad) ^ swz8;
                            bf[j][ks] = *(const bf16x8*)&lds[bBase + buf + r * 64 + c * 8];
                        }
                }
                bf16x8 af[2][2];
#pragma unroll
                for (int ii = 0; ii < 2; ++ii)
#pragma unroll
                    for (int ks = 0; ks < 2; ++ks) {
                        const int r = q * 32 + ii * 16 + l16;
                        const int c = (ks * 4 + quad) ^ swz8;
                        af[ii][ks] = *(const bf16x8*)&lds[aBase + buf + r * 64 + c * 8];
                    }
                if (q < 2) stageA(sa, q); else stageB(sb, q - 2);
                if (q == 3) asm volatile("s_waitcnt vmcnt(4)" ::: "memory");
                __builtin_amdgcn_s_barrier();
                __builtin_amdgcn_s_setprio(1);
#pragma unroll
                for (int ks = 0; ks < 2; ++ks)
#pragma unroll
                    for (int ii = 0; ii < 2; ++ii)
#pragma unroll
                        for (int j = 0; j < 4; ++j)
                            acc[q * 2 + ii][j] = __builtin_amdgcn_mfma_f32_16x16x32_bf16(
                                af[ii][ks], bf[j][ks], acc[q * 2 + ii][j], 0, 0, 0);
                __builtin_amdgcn_s_setprio(0);
                __builtin_amdgcn_s_barrier();
            }
        }
    }

    // epilogue: C/D layout col=lane&15, row=quad*4+reg (m89/m91-verified)
    const int crow = m0 + wm * 128 + quad * 4;
    const int ccol = n0 + wn * 64 + l16;
#pragma unroll
    for (int rf = 0; rf < 8; ++rf)
#pragma unroll
        for (int j = 0; j < 4; ++j)
#pragma unroll
            for (int r = 0; r < 4; ++r)
                C[(size_t)(crow + rf * 16 + r) * N_DIM + ccol + j * 16] = acc[rf][j][r];
}

// ---- emergency fallback (only if ws too small) ------------------------------
__global__ void naive_kernel(const float* __restrict__ x, const int* __restrict__ packed,
                             const float* __restrict__ params, float* __restrict__ out) {
    int idx = blockIdx.x * blockDim.x + threadIdx.x;
    if (idx >= M_DIM * N_DIM) return;
    int m = idx / N_DIM, o = idx % N_DIM;
    const float* xr = x + (size_t)m * K_DIM;
    float sum = 0.f;
    for (int gi = 0; gi < K_DIM / 256; ++gi) {
        int g = o * (K_DIM / 256) + gi;
        float s = params[2 * g], z = params[2 * g + 1];
        const int* p = packed + (size_t)g * 128;
        const float* xx = xr + gi * 256;
        for (int j = 0; j < 128; ++j) {
            int v = p[j];
            sum += xx[2 * j]     * ((float)(v & 15) * s + z);
            sum += xx[2 * j + 1] * ((float)((v >> 4) & 15) * s + z);
        }
    }
    out[idx] = sum;
}

extern "C" void kernel_launch(void* const* d_in, const int* in_sizes, int n_in,
                              void* d_out, int out_size, void* d_ws, size_t ws_size,
                              hipStream_t stream) {
    const float* x      = (const float*)d_in[0];
    const int*   packed = (const int*)d_in[1];
    const float* params = (const float*)d_in[2];
    float* out = (float*)d_out;

    const size_t a_bytes = (size_t)M_DIM * K_DIM * 2;   // 67.1 MB bf16 x
    const size_t w_bytes = (size_t)N_DIM * K_DIM * 2;   // 33.6 MB bf16 W

    if (ws_size >= a_bytes + w_bytes) {
        ushort* Abf = (ushort*)d_ws;
        ushort* Wbf = (ushort*)((char*)d_ws + a_bytes);

        // 16384 convert blocks + 8192 dequant blocks
        prep_kernel<<<24576, 256, 0, stream>>>(x, packed, params, Abf, Wbf);

        // 32 M-tiles x 16 N-tiles = 512 blocks, XCD-swizzled inside kernel
        gemm_bt<<<512, 512, 0, stream>>>(Abf, Wbf, out);
    } else {
        int n = M_DIM * N_DIM;
        naive_kernel<<<(n + 255) / 256, 256, 0, stream>>>(x, packed, params, out);
    }
}

// Round 2
// 445.195 us; speedup vs baseline: 1.0601x; 1.0356x over previous
//
#include <hip/hip_runtime.h>
#include <hip/hip_bf16.h>

// out[b,s,o] = sum_i x[b,s,i] * w[o,i]  -- NT GEMM M=8192, N=4096, K=4096
// w dequantized from 4-bit groups (256 vals/group, 16 groups per output row).

#define M_DIM 8192
#define N_DIM 4096
#define K_DIM 4096

typedef __bf16 bf16x8 __attribute__((ext_vector_type(8)));
typedef float f32x4 __attribute__((ext_vector_type(4)));
typedef unsigned short us8 __attribute__((ext_vector_type(8)));

__device__ __forceinline__ unsigned short f2bf_rne(float f) {
    unsigned int u = __builtin_bit_cast(unsigned int, f);
    u += 0x7FFFu + ((u >> 16) & 1u);
    return (unsigned short)(u >> 16);
}

// ---- fused prepass (unchanged) ---------------------------------------------
__global__ void prep_kernel(const float* __restrict__ x,
                            const int* __restrict__ packed,
                            const float* __restrict__ params,
                            ushort* __restrict__ a,
                            ushort* __restrict__ w) {
    int b = blockIdx.x;
    if (b < 16384) {
        int j = b * 256 + threadIdx.x;        // ushort8 index
        float4 v0 = ((const float4*)x)[2 * j];
        float4 v1 = ((const float4*)x)[2 * j + 1];
        us8 o;
        o[0] = f2bf_rne(v0.x); o[1] = f2bf_rne(v0.y);
        o[2] = f2bf_rne(v0.z); o[3] = f2bf_rne(v0.w);
        o[4] = f2bf_rne(v1.x); o[5] = f2bf_rne(v1.y);
        o[6] = f2bf_rne(v1.z); o[7] = f2bf_rne(v1.w);
        ((us8*)a)[j] = o;
    } else {
        int j = (b - 16384) * 256 + threadIdx.x;   // int4 index
        int4 v = ((const int4*)packed)[j];
        int g = j >> 5;                            // 4 ints same group
        float s = params[2 * g], z = params[2 * g + 1];
        unsigned int o0, o1, o2, o3;
        o0 = (unsigned int)f2bf_rne((float)(v.x & 15) * s + z)
           | ((unsigned int)f2bf_rne((float)((v.x >> 4) & 15) * s + z) << 16);
        o1 = (unsigned int)f2bf_rne((float)(v.y & 15) * s + z)
           | ((unsigned int)f2bf_rne((float)((v.y >> 4) & 15) * s + z) << 16);
        o2 = (unsigned int)f2bf_rne((float)(v.z & 15) * s + z)
           | ((unsigned int)f2bf_rne((float)((v.z >> 4) & 15) * s + z) << 16);
        o3 = (unsigned int)f2bf_rne((float)(v.w & 15) * s + z)
           | ((unsigned int)f2bf_rne((float)((v.w >> 4) & 15) * s + z) << 16);
        ((uint4*)w)[j] = make_uint4(o0, o1, o2, o3);
    }
}

// ---- main GEMM: 256x256, BK=64, PIPELINED fragment reads, 2 barriers/tile --
// Round-1 post-mortem: lockstep phases serialized LDS port (2300 cy/tile) with
// MFMA (2480 cy/tile) -> 52% MfmaUtil. Fix: every MFMA cluster consumes frags
// issued >=1 phase earlier; ds_read port drains UNDER the MFMA clusters.
//
// Per tile t (buf = parity slot of t):
//   ph0: read bf1(t); read afB(t,ph1); stageA(t+1,h0); MFMA(ph0: afA, bf0c/bf1)
//   ph1: read afA(t,ph2);              stageA(t+1,h1); MFMA(ph1: afB, ...)
//        lgkmcnt(0); [mid barrier]   <- frees B-slot(t) for stage B(t+2)
//   ph2: read afB(t,ph3);              stageB(t+2,h0); MFMA(ph2: afA, ...)
//   ph3:                               stageB(t+2,h1)
//        vmcnt(4)+lgkmcnt(0); [tile barrier]  <- A(t+1),B(t+1) landed, all waves
//        read bf0n(t+1); read afA(t+1,ph0)    <- hidden under MFMA(ph3)
//        MFMA(ph3: afB, bf0c/bf1)
// Ledger: outstanding at tile-end = B(t+1):4 + A(t+1):4 + B(t+2):4 = 12;
// vmcnt(4) leaves B(t+2) in flight -> never drains to 0. Cross-wave RAW safe:
// each wave's own vmcnt precedes the barrier, so post-barrier reads see all
// waves' stages. WAR safe: every ds_read of a slot is lgkm-drained before the
// barrier that releases that slot's next writer. bf0 ping-pongs (bf0a/bf0b)
// across the tile boundary so MFMA(ph3) still sees tile t's ks=0 B-frags.
// Chunk-XOR swizzle unchanged (0 conflicts measured).
__global__ __launch_bounds__(512, 2) void gemm_bt(const ushort* __restrict__ A,
                                                  const ushort* __restrict__ B,
                                                  float* __restrict__ C) {
    __shared__ ushort lds[65536];   // 128 KiB: A slots [0,32768), B [32768,65536)

    const int tid  = threadIdx.x;
    const int w    = tid >> 6;           // wave 0..7
    const int lane = tid & 63;
    const int quad = lane >> 4;          // 0..3
    const int l16  = lane & 15;
    const int wm   = w >> 2;             // wave M index 0..1 (128 rows each)
    const int wn   = w & 3;              // wave N index 0..3 (64 cols each)

    // XCD-bijective swizzle: 512 blocks, 64 contiguous per XCD, B-panel-major.
    const int bid = blockIdx.x;
    const int sid = (bid & 7) * 64 + (bid >> 3);
    const int by  = sid & 31;            // M tile 0..31
    const int bx  = sid >> 5;            // N tile 0..15
    const int m0  = by * 256;
    const int n0  = bx * 256;

    // staging source: thread t covers half-row (t>>3), pre-swizzled chunk
    const int srow = tid >> 3;                       // 0..63
    const int scol = ((tid & 7) ^ (srow & 7)) * 8;
    const ushort* aS = A + (size_t)(m0 + srow) * K_DIM + scol;
    const ushort* bS = B + (size_t)(n0 + srow) * K_DIM + scol;

    f32x4 acc[8][4] = {};
    bf16x8 afA[2][2], afB[2][2];         // A frags, phase ping-pong
    bf16x8 bf0a[4], bf0b[4];             // B ks=0 frags, tile-parity ping-pong
    bf16x8 bf1[4];                       // B ks=1 frags (single buffer)

    auto stageA = [&](int t, int h) {
        const int kc   = (t < 64 ? t : 63) * 64;
        const int slot = ((t & 1) * 2 + h) * 8192;
#pragma unroll
        for (int l = 0; l < 2; ++l)
            __builtin_amdgcn_global_load_lds(
                (const __attribute__((address_space(1))) void*)(aS + (size_t)(h * 128 + l * 64) * K_DIM + kc),
                (__attribute__((address_space(3))) void*)(lds + slot + (l * 512 + w * 64) * 8),
                16, 0, 0);
    };
    auto stageB = [&](int t, int h) {
        const int kc   = (t < 64 ? t : 63) * 64;
        const int slot = 32768 + ((t & 1) * 2 + h) * 8192;
#pragma unroll
        for (int l = 0; l < 2; ++l)
            __builtin_amdgcn_global_load_lds(
                (const __attribute__((address_space(1))) void*)(bS + (size_t)(h * 128 + l * 64) * K_DIM + kc),
                (__attribute__((address_space(3))) void*)(lds + slot + (l * 512 + w * 64) * 8),
                16, 0, 0);
    };

    const int aBase = wm * 8192;                   // this wave's A half-slot
    const int bBase = 32768 + (wn >> 1) * 8192;    // this wave's B half-slot
    const int bR0   = (wn & 1) * 64;
    const int swz8  = l16 & 7;

    auto readAF = [&](bf16x8 (&dst)[2][2], int buf, int ph) {
#pragma unroll
        for (int ii = 0; ii < 2; ++ii)
#pragma unroll
            for (int ks = 0; ks < 2; ++ks)
                dst[ii][ks] = *(const bf16x8*)&lds[aBase + buf +
                    (ph * 32 + ii * 16 + l16) * 64 + ((ks * 4 + quad) ^ swz8) * 8];
    };
    auto readBF0 = [&](bf16x8 (&dst)[4], int buf) {
#pragma unroll
        for (int j = 0; j < 4; ++j)
            dst[j] = *(const bf16x8*)&lds[bBase + buf +
                (bR0 + j * 16 + l16) * 64 + (quad ^ swz8) * 8];
    };
    auto readBF1 = [&](int buf) {
#pragma unroll
        for (int j = 0; j < 4; ++j)
            bf1[j] = *(const bf16x8*)&lds[bBase + buf +
                (bR0 + j * 16 + l16) * 64 + ((4 + quad) ^ swz8) * 8];
    };

    // MFMA cluster for phase PH (compile-time): rows [PH*32, PH*32+32)
#define MFMA_PH(PH, AF, BF0)                                                   \
    do {                                                                       \
        __builtin_amdgcn_s_setprio(1);                                         \
        _Pragma("unroll")                                                      \
        for (int ii = 0; ii < 2; ++ii)                                         \
            _Pragma("unroll")                                                  \
            for (int j = 0; j < 4; ++j)                                        \
                acc[(PH) * 2 + ii][j] = __builtin_amdgcn_mfma_f32_16x16x32_bf16( \
                    AF[ii][0], BF0[j], acc[(PH) * 2 + ii][j], 0, 0, 0);        \
        _Pragma("unroll")                                                      \
        for (int ii = 0; ii < 2; ++ii)                                         \
            _Pragma("unroll")                                                  \
            for (int j = 0; j < 4; ++j)                                        \
                acc[(PH) * 2 + ii][j] = __builtin_amdgcn_mfma_f32_16x16x32_bf16( \
                    AF[ii][1], bf1[j], acc[(PH) * 2 + ii][j], 0, 0, 0);        \
        __builtin_amdgcn_s_setprio(0);                                         \
    } while (0)

    // prologue: stage B0,A0,B1 (12 loads); drain to 4 (B1 in flight); barrier;
    // first-tile frag reads (one-time exposed burst).
    stageB(0, 0); stageB(0, 1); stageA(0, 0); stageA(0, 1); stageB(1, 0); stageB(1, 1);
    asm volatile("s_waitcnt vmcnt(4)" ::: "memory");
    __builtin_amdgcn_s_barrier();
    asm volatile("" ::: "memory");
    readBF0(bf0a, 0);
    readAF(afA, 0, 0);

#define TILE(T, BUF, NBUF, BF0C, BF0N)                                         \
    do {                                                                       \
        const int t = (T);                                                     \
        /* ph0 */                                                              \
        readBF1(BUF);                                                          \
        readAF(afB, BUF, 1);                                                   \
        stageA(t + 1, 0);                                                      \
        MFMA_PH(0, afA, BF0C);                                                 \
        /* ph1 */                                                              \
        readAF(afA, BUF, 2);                                                   \
        stageA(t + 1, 1);                                                      \
        MFMA_PH(1, afB, BF0C);                                                 \
        asm volatile("s_waitcnt lgkmcnt(0)" ::: "memory");                     \
        __builtin_amdgcn_sched_barrier(0);                                     \
        __builtin_amdgcn_s_barrier();       /* mid: B-slot(t) free */          \
        asm volatile("" ::: "memory");                                         \
        /* ph2 */                                                              \
        readAF(afB, BUF, 3);                                                   \
        stageB(t + 2, 0);                                                      \
        MFMA_PH(2, afA, BF0C);                                                 \
        /* ph3 */                                                              \
        stageB(t + 2, 1);                                                      \
        asm volatile("s_waitcnt vmcnt(4) lgkmcnt(0)" ::: "memory");            \
        __builtin_amdgcn_s_barrier();       /* tile: buf(t+1) ready */         \
        asm volatile("" ::: "memory");                                         \
        if (t < 63) { readBF0(BF0N, NBUF); readAF(afA, NBUF, 0); }             \
        __builtin_amdgcn_sched_barrier(0);                                     \
        MFMA_PH(3, afB, BF0C);                                                 \
    } while (0)

#pragma unroll 1
    for (int tt = 0; tt < 64; tt += 2) {
        TILE(tt,     0,     16384, bf0a, bf0b);
        TILE(tt + 1, 16384, 0,     bf0b, bf0a);
    }
#undef TILE
#undef MFMA_PH

    // epilogue: C/D layout col=lane&15, row=quad*4+reg (m89/m91-verified)
    const int crow = m0 + wm * 128 + quad * 4;
    const int ccol = n0 + wn * 64 + l16;
#pragma unroll
    for (int rf = 0; rf < 8; ++rf)
#pragma unroll
        for (int j = 0; j < 4; ++j)
#pragma unroll
            for (int r = 0; r < 4; ++r)
                C[(size_t)(crow + rf * 16 + r) * N_DIM + ccol + j * 16] = acc[rf][j][r];
}

// ---- emergency fallback (only if ws too small) ------------------------------
__global__ void naive_kernel(const float* __restrict__ x, const int* __restrict__ packed,
                             const float* __restrict__ params, float* __restrict__ out) {
    int idx = blockIdx.x * blockDim.x + threadIdx.x;
    if (idx >= M_DIM * N_DIM) return;
    int m = idx / N_DIM, o = idx % N_DIM;
    const float* xr = x + (size_t)m * K_DIM;
    float sum = 0.f;
    for (int gi = 0; gi < K_DIM / 256; ++gi) {
        int g = o * (K_DIM / 256) + gi;
        float s = params[2 * g], z = params[2 * g + 1];
        const int* p = packed + (size_t)g * 128;
        const float* xx = xr + gi * 256;
        for (int j = 0; j < 128; ++j) {
            int v = p[j];
            sum += xx[2 * j]     * ((float)(v & 15) * s + z);
            sum += xx[2 * j + 1] * ((float)((v >> 4) & 15) * s + z);
        }
    }
    out[idx] = sum;
}

extern "C" void kernel_launch(void* const* d_in, const int* in_sizes, int n_in,
                              void* d_out, int out_size, void* d_ws, size_t ws_size,
                              hipStream_t stream) {
    const float* x      = (const float*)d_in[0];
    const int*   packed = (const int*)d_in[1];
    const float* params = (const float*)d_in[2];
    float* out = (float*)d_out;

    const size_t a_bytes = (size_t)M_DIM * K_DIM * 2;   // 67.1 MB bf16 x
    const size_t w_bytes = (size_t)N_DIM * K_DIM * 2;   // 33.6 MB bf16 W

    if (ws_size >= a_bytes + w_bytes) {
        ushort* Abf = (ushort*)d_ws;
        ushort* Wbf = (ushort*)((char*)d_ws + a_bytes);

        prep_kernel<<<24576, 256, 0, stream>>>(x, packed, params, Abf, Wbf);

        // 32 M-tiles x 16 N-tiles = 512 blocks, XCD-swizzled inside kernel
        gemm_bt<<<512, 512, 0, stream>>>(Abf, Wbf, out);
    } else {
        int n = M_DIM * N_DIM;
        naive_kernel<<<(n + 255) / 256, 256, 0, stream>>>(x, packed, params, out);
    }
}